// Round 1
// baseline (85.292 us; speedup 1.0000x reference)
//
#include <hip/hip_runtime.h>
#include <math.h>

#define MAXR 100.0f
#define LOG2E 1.4426950408889634f
// Fixed shapes: B=4, C=64, H=64, W=64; conv (2,64,3,3) OIHW, SAME.

__device__ __forceinline__ float bcast_lane(float v, int i) {
    return __int_as_float(__builtin_amdgcn_readlane(__float_as_int(v), i));
}
__device__ __forceinline__ float exp2_fast(float x) { return __builtin_amdgcn_exp2f(x); }
__device__ __forceinline__ float rcp_fast(float x)  { return __builtin_amdgcn_rcpf(x); }

__device__ __forceinline__ float tanh_fast(float s) {
    // tanh(s) = sign(s) * (1 - 2/(e^{2|s|}+1)); E=inf -> t=1 exactly
    float E = exp2_fast(2.0f * LOG2E * fabsf(s));
    float t = fmaf(-2.0f, rcp_fast(E + 1.0f), 1.0f);
    return copysignf(t, s);
}

// Single fused kernel, minimal structure. 4096 blocks x 256 threads (4 waves).
// Block = 4 consecutive-w pixels (same b,h); ONE pixel per wave; lane = channel.
// LDS: only the 64c x 3r x 6w conv window (4.9 KB). Pairwise broadcast via
// v_readlane (VALU), conv weights straight from global (L2-hot).
__global__ __launch_bounds__(256) void dsf_fused(const float* __restrict__ x,
                                                 const float* __restrict__ wg,
                                                 const float* __restrict__ bias,
                                                 float* __restrict__ out) {
    __shared__ float xs[64 * 19];       // [c][r*6+wt], stride 19 (gcd(19,32)=1)

    const int tid  = threadIdx.x;
    const int lane = tid & 63;
    const int wave = tid >> 6;

    const int p0 = blockIdx.x * 4;      // b*4096 + h*64 + w0, w0 multiple of 4
    const int b  = p0 >> 12;
    const int h  = (p0 >> 6) & 63;
    const int w0 = p0 & 63;

    // per-lane conv weights (channel = lane): 18 dwords from L2 (reused chip-wide)
    float wr0[9], wr1[9];
    #pragma unroll
    for (int k = 0; k < 9; ++k) {
        wr0[k] = wg[lane * 9 + k];
        wr1[k] = wg[576 + lane * 9 + k];
    }
    const float b0 = bias[0], b1 = bias[1];

    // stage x[b, :, h-1:h+2, w0-1:w0+4] zero-padded into xs
    const float* xbase = x + b * 262144;
    for (int e = tid; e < 1152; e += 256) {
        int c   = e / 18;
        int rem = e - c * 18;
        int r   = rem / 6;
        int wt  = rem - r * 6;
        int hh  = h + r - 1;
        int ww  = w0 - 1 + wt;
        float v = 0.f;
        if (hh >= 0 && hh < 64 && ww >= 0 && ww < 64)
            v = xbase[c * 4096 + hh * 64 + ww];
        xs[c * 19 + rem] = v;
    }
    __syncthreads();

    // ---- conv for this wave's pixel: lane sums its channel's 9 taps ----
    const float* xc = xs + lane * 19;
    float a0 = 0.f, a1 = 0.f;
    #pragma unroll
    for (int r = 0; r < 3; ++r) {
        #pragma unroll
        for (int t = 0; t < 3; ++t) {
            float xv = xc[r * 6 + wave + t];
            a0 = fmaf(xv, wr0[r * 3 + t], a0);
            a1 = fmaf(xv, wr1[r * 3 + t], a1);
        }
    }
    #pragma unroll
    for (int off = 32; off; off >>= 1) {
        a0 += __shfl_xor(a0, off, 64);
        a1 += __shfl_xor(a1, off, 64);
    }
    const float al = MAXR * tanh_fast(a0 + b0);    // alpha (wave-uniform)
    const float be = MAXR * tanh_fast(a1 + b1);    // beta
    const float aa = fabsf(al);
    const float c2 = 2.0f * LOG2E * aa;            // t = 1 - 2/(2^(c2*|d|)+1)

    const float xj = xc[6 + wave + 1];             // x[b, lane, h, w0+wave]

    // ---- pairwise: A_j = sum_i |be*x_i - x_j| * tanh(aa*|...|), 4 chains ----
    float A0 = 0.f, A1 = 0.f, A2 = 0.f, A3 = 0.f;
    #pragma unroll
    for (int i = 0; i < 16; ++i) {
        float s0 = bcast_lane(xj, i);
        float s1 = bcast_lane(xj, i + 16);
        float s2 = bcast_lane(xj, i + 32);
        float s3 = bcast_lane(xj, i + 48);
        float d0 = fmaf(be, s0, -xj);
        float d1 = fmaf(be, s1, -xj);
        float d2 = fmaf(be, s2, -xj);
        float d3 = fmaf(be, s3, -xj);
        float E0 = exp2_fast(c2 * fabsf(d0));
        float E1 = exp2_fast(c2 * fabsf(d1));
        float E2 = exp2_fast(c2 * fabsf(d2));
        float E3 = exp2_fast(c2 * fabsf(d3));
        float r0 = rcp_fast(E0 + 1.f);
        float r1 = rcp_fast(E1 + 1.f);
        float r2 = rcp_fast(E2 + 1.f);
        float r3 = rcp_fast(E3 + 1.f);
        float u0 = fmaf(-2.f, r0, 1.f);
        float u1 = fmaf(-2.f, r1, 1.f);
        float u2 = fmaf(-2.f, r2, 1.f);
        float u3 = fmaf(-2.f, r3, 1.f);
        A0 = fmaf(fabsf(d0), u0, A0);
        A1 = fmaf(fabsf(d1), u1, A1);
        A2 = fmaf(fabsf(d2), u2, A2);
        A3 = fmaf(fabsf(d3), u3, A3);
    }
    float A = (A0 + A1) + (A2 + A3);

    // logits: g_j = max(-A*|alpha|/64, -100)  (sign(alpha) cancels exactly)
    float gl = fmaxf(-A * aa * (1.0f / 64.0f), -MAXR);

    float gm = gl;
    #pragma unroll
    for (int off = 32; off; off >>= 1) gm = fmaxf(gm, __shfl_xor(gm, off, 64));
    float ew  = exp2_fast((gl - gm) * LOG2E);
    float den = ew, num = xj * ew;
    #pragma unroll
    for (int off = 32; off; off >>= 1) {
        den += __shfl_xor(den, off, 64);
        num += __shfl_xor(num, off, 64);
    }
    if (lane == 0) out[p0 + wave] = num * rcp_fast(den);   // den >= 1
}

extern "C" void kernel_launch(void* const* d_in, const int* in_sizes, int n_in,
                              void* d_out, int out_size, void* d_ws, size_t ws_size,
                              hipStream_t stream) {
    const float* x      = (const float*)d_in[0];   // (4,64,64,64)
    const float* conv_w = (const float*)d_in[1];   // (2,64,3,3)
    const float* conv_b = (const float*)d_in[2];   // (2,)
    float* out = (float*)d_out;                    // (4,1,64,64)
    (void)d_ws; (void)ws_size;

    dsf_fused<<<4096, 256, 0, stream>>>(x, conv_w, conv_b, out);
}